// Round 1
// baseline (96.252 us; speedup 1.0000x reference)
//
#include <hip/hip_runtime.h>
#include <math.h>

// Problem constants
constexpr int kB   = 128;
constexpr int kP   = 2048;
constexpr int kRES = 4096;
constexpr int kF   = 256;   // ph_feature_dim
constexpr int kH   = 1024;  // hidden
constexpr int kSPLIT = 16;  // blocks per batch for kernel 1
constexpr float kLN_EPS = 1e-5f;

__device__ __forceinline__ float gelu_exact(float x) {
    return 0.5f * x * (1.0f + erff(x * 0.70710678118654752f));
}

// ---------------------------------------------------------------------------
// Kernel 1: partial sums over masked rows of g = GELU(LN(pd @ W1 + b1)).
// grid = (kSPLIT, kB), block = 256. Each wave owns one row at a time;
// lane l holds features f = 4l..4l+3. Wave-level shuffle reduce for LN.
// Deterministic: every block writes its own partial[b][s][256] (zeros if no work).
// ---------------------------------------------------------------------------
__global__ __launch_bounds__(256) void k1_pd_partial(
    const float* __restrict__ pd, const int* __restrict__ pd_lengths,
    const float* __restrict__ W1, const float* __restrict__ b1,
    const float* __restrict__ ln_g, const float* __restrict__ ln_b,
    float* __restrict__ partial)
{
    const int b    = blockIdx.y;
    const int s    = blockIdx.x;
    const int tid  = threadIdx.x;
    const int wave = tid >> 6;
    const int lane = tid & 63;
    const int len  = pd_lengths[b];

    // Per-lane weight fragments: f = 4*lane + j
    const float4* W14 = (const float4*)W1;             // W1 is [3][256] row-major
    const float4 w0 = W14[lane];
    const float4 w1 = W14[64 + lane];
    const float4 w2 = W14[128 + lane];
    const float4 bb = ((const float4*)b1)[lane];
    const float4 gg = ((const float4*)ln_g)[lane];
    const float4 be = ((const float4*)ln_b)[lane];

    float a0 = 0.f, a1 = 0.f, a2 = 0.f, a3 = 0.f;

    const int chain = s * 4 + wave;                    // 0..63, stride 64 over P
    for (int p = chain; p < len; p += kSPLIT * 4) {
        const float* row = pd + ((size_t)b * kP + p) * 3;
        const float x0 = row[0];
        const float x1 = row[1];
        const float x2 = row[2];

        float h0 = fmaf(x2, w2.x, fmaf(x1, w1.x, fmaf(x0, w0.x, bb.x)));
        float h1 = fmaf(x2, w2.y, fmaf(x1, w1.y, fmaf(x0, w0.y, bb.y)));
        float h2 = fmaf(x2, w2.z, fmaf(x1, w1.z, fmaf(x0, w0.z, bb.z)));
        float h3 = fmaf(x2, w2.w, fmaf(x1, w1.w, fmaf(x0, w0.w, bb.w)));

        float ps1 = (h0 + h1) + (h2 + h3);
        float ps2 = fmaf(h0, h0, fmaf(h1, h1, fmaf(h2, h2, h3 * h3)));
        #pragma unroll
        for (int off = 32; off > 0; off >>= 1) {
            ps1 += __shfl_xor(ps1, off);
            ps2 += __shfl_xor(ps2, off);
        }
        const float mu   = ps1 * (1.f / 256.f);
        const float var  = fmaf(ps2, 1.f / 256.f, -mu * mu);  // biased var
        const float rstd = rsqrtf(var + kLN_EPS);

        const float y0 = fmaf((h0 - mu) * rstd, gg.x, be.x);
        const float y1 = fmaf((h1 - mu) * rstd, gg.y, be.y);
        const float y2 = fmaf((h2 - mu) * rstd, gg.z, be.z);
        const float y3 = fmaf((h3 - mu) * rstd, gg.w, be.w);

        a0 += gelu_exact(y0);
        a1 += gelu_exact(y1);
        a2 += gelu_exact(y2);
        a3 += gelu_exact(y3);
    }

    __shared__ float red[4][256];
    ((float4*)red[wave])[lane] = make_float4(a0, a1, a2, a3);
    __syncthreads();
    const float v = (red[0][tid] + red[1][tid]) + (red[2][tid] + red[3][tid]);
    partial[((size_t)(b * kSPLIT + s)) * 256 + tid] = v;
}

// ---------------------------------------------------------------------------
// Kernel 2: build combined[b][1024] = concat(pd_pooled, betti_feat, pi_feat).
// grid = kB blocks, 256 threads. Conv1d mean collapses to even/odd sums.
// ---------------------------------------------------------------------------
__global__ __launch_bounds__(256) void k2_combined(
    const float* __restrict__ partial, const int* __restrict__ pd_lengths,
    const float* __restrict__ W2, const float* __restrict__ b2,
    const int* __restrict__ betti, const float* __restrict__ betti_table,
    const float* __restrict__ pimg, const float* __restrict__ conv_w,
    const float* __restrict__ conv_b, float* __restrict__ combined)
{
    const int b    = blockIdx.x;
    const int tid  = threadIdx.x;
    const int wave = tid >> 6;
    const int lane = tid & 63;

    // --- PI even/odd sums over 4096 elements ---
    const float4* x4 = (const float4*)(pimg + (size_t)b * kRES);
    float se = 0.f, so = 0.f;
    #pragma unroll
    for (int j = 0; j < 4; ++j) {
        const float4 v = x4[tid + j * 256];
        se += v.x + v.z;
        so += v.y + v.w;
    }
    #pragma unroll
    for (int off = 32; off > 0; off >>= 1) {
        se += __shfl_xor(se, off);
        so += __shfl_xor(so, off);
    }
    __shared__ float sred[2][4];
    if (lane == 0) { sred[0][wave] = se; sred[1][wave] = so; }

    // --- pooled mean of g over masked rows ---
    __shared__ float ml[256];
    const int len = pd_lengths[b];
    float sm = 0.f;
    #pragma unroll
    for (int s = 0; s < kSPLIT; ++s)
        sm += partial[((size_t)(b * kSPLIT + s)) * 256 + tid];
    ml[tid] = (len > 0) ? (sm / (float)len) : 0.f;
    __syncthreads();

    se = (sred[0][0] + sred[0][1]) + (sred[0][2] + sred[0][3]);
    so = (sred[1][0] + sred[1][1]) + (sred[1][2] + sred[1][3]);

    // --- pd_pooled = mean_g @ W2 + b2 (or 0 if empty) ---
    float acc = 0.f;
    #pragma unroll 4
    for (int f = 0; f < kF; ++f)
        acc = fmaf(ml[f], W2[(size_t)f * 256 + tid], acc);
    combined[(size_t)b * kH + tid] = (len > 0) ? (acc + b2[tid]) : 0.f;

    // --- betti: clamp -> gather -> mean over 3 dims ---
    const int i0 = min(max(betti[b * 3 + 0], 0), 9);
    const int i1 = min(max(betti[b * 3 + 1], 0), 9);
    const int i2 = min(max(betti[b * 3 + 2], 0), 9);
    combined[(size_t)b * kH + 256 + tid] =
        (betti_table[i0 * 256 + tid] + betti_table[i1 * 256 + tid] +
         betti_table[i2 * 256 + tid]) * (1.f / 3.f);

    // --- pi_feat: closed-form conv mean ---
    // k=0: S_even - x[4094]; k=1: S_odd - x[4095]; k=2: S_even; k=3: S_odd; k=4: S_even - x[0]
    const float x0  = pimg[(size_t)b * kRES + 0];
    const float xe  = pimg[(size_t)b * kRES + 4094];
    const float xo  = pimg[(size_t)b * kRES + 4095];
    #pragma unroll
    for (int u = 0; u < 2; ++u) {
        const int c = tid + u * 256;
        const float* w = conv_w + (size_t)c * 5;
        const float v = w[0] * (se - xe) + w[1] * (so - xo) + w[2] * se +
                        w[3] * so + w[4] * (se - x0);
        combined[(size_t)b * kH + 512 + c] = v * (1.f / 2048.f) + conv_b[c];
    }
}

// ---------------------------------------------------------------------------
// Kernel 3: out = combined @ Wo + bo.  grid = (16 n-tiles, 8 b-tiles),
// 256 threads. C tile (16 x 1024) staged in 64KB LDS; Wo streamed as float4.
// Thread: 1 batch x 4 cols, K-loop unrolled by 4 (one b128 LDS read / 4 k).
// ---------------------------------------------------------------------------
__global__ __launch_bounds__(256) void k3_outproj(
    const float* __restrict__ combined, const float* __restrict__ Wo,
    const float* __restrict__ bo, float* __restrict__ out)
{
    const int nt  = blockIdx.x;      // 0..15
    const int bt  = blockIdx.y;      // 0..7
    const int tid = threadIdx.x;
    const int b0  = bt * 16;
    const int n0  = nt * 64;

    __shared__ float4 cl4[16 * 256];   // 16 rows x 1024 floats = 64 KiB
    const float4* C4 = (const float4*)(combined + (size_t)b0 * kH);
    #pragma unroll
    for (int j = 0; j < 16; ++j)
        cl4[tid + j * 256] = C4[tid + j * 256];
    __syncthreads();

    const int bl = tid >> 4;                  // local batch 0..15
    const int cg = tid & 15;                  // col group (4 cols)
    const float4* Wo4 = (const float4*)Wo;    // row k: 256 float4
    const int wbase = (n0 >> 2) + cg;

    float4 acc = make_float4(0.f, 0.f, 0.f, 0.f);
    for (int k4 = 0; k4 < 256; ++k4) {
        const float4 cv = cl4[bl * 256 + k4];
        const int k = k4 * 4;
        const float4 q0 = Wo4[(size_t)(k + 0) * 256 + wbase];
        const float4 q1 = Wo4[(size_t)(k + 1) * 256 + wbase];
        const float4 q2 = Wo4[(size_t)(k + 2) * 256 + wbase];
        const float4 q3 = Wo4[(size_t)(k + 3) * 256 + wbase];
        acc.x = fmaf(cv.x, q0.x, acc.x); acc.y = fmaf(cv.x, q0.y, acc.y);
        acc.z = fmaf(cv.x, q0.z, acc.z); acc.w = fmaf(cv.x, q0.w, acc.w);
        acc.x = fmaf(cv.y, q1.x, acc.x); acc.y = fmaf(cv.y, q1.y, acc.y);
        acc.z = fmaf(cv.y, q1.z, acc.z); acc.w = fmaf(cv.y, q1.w, acc.w);
        acc.x = fmaf(cv.z, q2.x, acc.x); acc.y = fmaf(cv.z, q2.y, acc.y);
        acc.z = fmaf(cv.z, q2.z, acc.z); acc.w = fmaf(cv.z, q2.w, acc.w);
        acc.x = fmaf(cv.w, q3.x, acc.x); acc.y = fmaf(cv.w, q3.y, acc.y);
        acc.z = fmaf(cv.w, q3.z, acc.z); acc.w = fmaf(cv.w, q3.w, acc.w);
    }

    const float4 bv = ((const float4*)bo)[wbase];
    float4 r;
    r.x = acc.x + bv.x; r.y = acc.y + bv.y;
    r.z = acc.z + bv.z; r.w = acc.w + bv.w;
    ((float4*)(out + (size_t)(b0 + bl) * kH + n0))[cg] = r;
}

// ---------------------------------------------------------------------------
extern "C" void kernel_launch(void* const* d_in, const int* in_sizes, int n_in,
                              void* d_out, int out_size, void* d_ws, size_t ws_size,
                              hipStream_t stream) {
    const float* pd   = (const float*)d_in[0];
    const int*   plen = (const int*)  d_in[1];
    const int*   bnum = (const int*)  d_in[2];
    const float* pimg = (const float*)d_in[3];
    const float* W1   = (const float*)d_in[4];
    const float* b1   = (const float*)d_in[5];
    const float* lng  = (const float*)d_in[6];
    const float* lnb  = (const float*)d_in[7];
    const float* W2   = (const float*)d_in[8];
    const float* b2   = (const float*)d_in[9];
    const float* btab = (const float*)d_in[10];
    const float* cw   = (const float*)d_in[11];
    const float* cb   = (const float*)d_in[12];
    const float* Wo   = (const float*)d_in[13];
    const float* bo   = (const float*)d_in[14];
    float* out = (float*)d_out;

    float* partial  = (float*)d_ws;                          // kB*kSPLIT*256 floats (2 MiB)
    float* combined = partial + (size_t)kB * kSPLIT * 256;   // kB*kH floats (512 KiB)

    k1_pd_partial<<<dim3(kSPLIT, kB), 256, 0, stream>>>(pd, plen, W1, b1, lng, lnb, partial);
    k2_combined<<<dim3(kB), 256, 0, stream>>>(partial, plen, W2, b2, bnum, btab, pimg, cw, cb, combined);
    k3_outproj<<<dim3(16, 8), 256, 0, stream>>>(combined, Wo, bo, out);
}